// Round 1
// baseline (497.439 us; speedup 1.0000x reference)
//
#include <hip/hip_runtime.h>
#include <math.h>

// LIF network: B=128, N_in=784, N_hid=256, N_out=10, T=500
//   v <- v + (I - v)*0.1 ; s = sigmoid(5*(v-1))
// Structure: time-hoisted big GEMM (M=64000,K=784,N=256) -> per-(b,h) scan ->
// skinny GEMM (K=256,N=10) -> per-(b,o) scan -> outputs.
// Workspace layout (fp32): I_h [64000][256] (65.5MB, reused in-place as s_h),
//                          I_o [64000][10]  (2.56MB).  Total 68.1 MB.

#define B_   128
#define NIN  784
#define NH   256
#define NO   10
#define T_   500
#define M_   (B_ * T_)   // 64000

__device__ __forceinline__ float sigmoid5(float v) {
    return 1.0f / (1.0f + __expf(-5.0f * (v - 1.0f)));
}

// ---------------- Phase A: hidden GEMM ----------------
// I_h[m][h], m = b*T+t.  A[m][k] = spikes[b][k][t] (transposed read, t-contig
// in memory -> coalesced along m).  Bmat[k][h] = relu(w_ih[k][h]).
// 128x128 tile, BK=8, 256 threads, 8x8 micro-tile per thread (fp32 FMA).
__global__ __launch_bounds__(256, 2) void gemm_hidden(
    const float* __restrict__ spikes,   // [128][784][500]
    const float* __restrict__ w_ih,     // [784][256]
    float* __restrict__ I_h)            // [64000][256]
{
    __shared__ __align__(16) float As[8][128];
    __shared__ __align__(16) float Bs[8][128];

    const int row0 = blockIdx.x * 128;   // 500 tiles (exact)
    const int col0 = blockIdx.y * 128;   // 2 tiles (exact)
    const int tid  = threadIdx.x;
    const int tm = tid & 15;
    const int tn = tid >> 4;

    float acc[8][8];
#pragma unroll
    for (int i = 0; i < 8; ++i)
#pragma unroll
        for (int j = 0; j < 8; ++j) acc[i][j] = 0.f;

    for (int k0 = 0; k0 < NIN; k0 += 8) {  // 98 iterations (exact)
        // ---- stage A (with b,t decode) and B (with relu) ----
#pragma unroll
        for (int r = 0; r < 4; ++r) {
            int e = r * 256 + tid;
            int k = e >> 7;          // 0..7
            int x = e & 127;         // 0..127
            unsigned gm = (unsigned)(row0 + x);
            unsigned b  = gm / 500u;           // compiler magic-div
            unsigned t  = gm - b * 500u;
            As[k][x] = spikes[(size_t)b * (NIN * T_) + (size_t)(k0 + k) * T_ + t];
            Bs[k][x] = fmaxf(0.f, w_ih[(size_t)(k0 + k) * NH + col0 + x]);
        }
        __syncthreads();

#pragma unroll
        for (int kk = 0; kk < 8; ++kk) {
            const float4 a0 = *reinterpret_cast<const float4*>(&As[kk][tm * 4]);
            const float4 a1 = *reinterpret_cast<const float4*>(&As[kk][tm * 4 + 64]);
            const float4 b0 = *reinterpret_cast<const float4*>(&Bs[kk][tn * 4]);
            const float4 b1 = *reinterpret_cast<const float4*>(&Bs[kk][tn * 4 + 64]);
            float av[8] = {a0.x, a0.y, a0.z, a0.w, a1.x, a1.y, a1.z, a1.w};
            float bv[8] = {b0.x, b0.y, b0.z, b0.w, b1.x, b1.y, b1.z, b1.w};
#pragma unroll
            for (int i = 0; i < 8; ++i)
#pragma unroll
                for (int j = 0; j < 8; ++j)
                    acc[i][j] = fmaf(av[i], bv[j], acc[i][j]);
        }
        __syncthreads();  // protect LDS before next stage
    }

    // ---- epilogue: two float4 stores per micro-row ----
#pragma unroll
    for (int i = 0; i < 8; ++i) {
        int gr = row0 + ((i < 4) ? (tm * 4 + i) : (64 + tm * 4 + (i - 4)));
        float4 lo = make_float4(acc[i][0], acc[i][1], acc[i][2], acc[i][3]);
        float4 hi = make_float4(acc[i][4], acc[i][5], acc[i][6], acc[i][7]);
        *reinterpret_cast<float4*>(&I_h[(size_t)gr * NH + col0 + tn * 4]) = lo;
        *reinterpret_cast<float4*>(&I_h[(size_t)gr * NH + col0 + 64 + tn * 4]) = hi;
    }
}

// ---------------- Phase B: hidden LIF scan (in place) ----------------
// 32768 independent chains (b,h). Thread handles one chain over t.
// Reads I_h[(b*T+t)*256+h] (coalesced over h), writes s_h in place.
__global__ void lif_hidden(float* __restrict__ I_h)
{
    const int b = blockIdx.x >> 1;                       // 256 blocks x 128 thr
    const int h = ((blockIdx.x & 1) << 7) + threadIdx.x;
    float v = 0.f;
    size_t base = (size_t)b * T_ * NH + h;
#pragma unroll 4
    for (int t = 0; t < T_; ++t) {
        float I = I_h[base + (size_t)t * NH];
        v += (I - v) * 0.1f;
        I_h[base + (size_t)t * NH] = sigmoid5(v);
    }
}

// ---------------- Phase C: output GEMM ----------------
// I_o[m][o] = sum_h s_h[m][h] * relu(w_ho[h][o]).  K=256, N=10.
// One wave per row; lane l holds s_h[m][4l..4l+3] and w_ho[4l+i][*] in regs;
// butterfly reduce 10 accumulators across 64 lanes.
__global__ __launch_bounds__(256) void gemm_out(
    const float* __restrict__ s_h,     // [64000][256]
    const float* __restrict__ w_ho,    // [256][10]
    float* __restrict__ I_o)           // [64000][10]
{
    const int lane   = threadIdx.x & 63;
    const int wave   = blockIdx.x * 4 + (threadIdx.x >> 6);
    const int nwaves = gridDim.x * 4;

    float w[4][NO];
#pragma unroll
    for (int i = 0; i < 4; ++i)
#pragma unroll
        for (int o = 0; o < NO; ++o)
            w[i][o] = fmaxf(0.f, w_ho[(size_t)(lane * 4 + i) * NO + o]);

    for (int m = wave; m < M_; m += nwaves) {
        const float4 s = *reinterpret_cast<const float4*>(&s_h[(size_t)m * NH + lane * 4]);
        float acc[NO];
#pragma unroll
        for (int o = 0; o < NO; ++o) {
            acc[o] = s.x * w[0][o] + s.y * w[1][o] + s.z * w[2][o] + s.w * w[3][o];
        }
#pragma unroll
        for (int o = 0; o < NO; ++o) {
            float v = acc[o];
            v += __shfl_xor(v, 1);
            v += __shfl_xor(v, 2);
            v += __shfl_xor(v, 4);
            v += __shfl_xor(v, 8);
            v += __shfl_xor(v, 16);
            v += __shfl_xor(v, 32);
            acc[o] = v;
        }
        float outv = 0.f;
#pragma unroll
        for (int o = 0; o < NO; ++o)
            outv = (lane == o) ? acc[o] : outv;   // cndmask chain, no scratch
        if (lane < NO) I_o[(size_t)m * NO + lane] = outv;
    }
}

// ---------------- Phase D: output LIF scan + outputs ----------------
// 1280 chains (b,o). Writes output_spikes [b][o][t] and firing_rates [b][o].
__global__ void lif_out(const float* __restrict__ I_o, float* __restrict__ out)
{
    const int idx = blockIdx.x * 256 + threadIdx.x;
    if (idx >= B_ * NO) return;
    const int b = idx / NO;
    const int o = idx - b * NO;
    float v = 0.f, sum = 0.f;
#pragma unroll 4
    for (int t = 0; t < T_; ++t) {
        float I = I_o[((size_t)b * T_ + t) * NO + o];
        v += (I - v) * 0.1f;
        float s = sigmoid5(v);
        out[(size_t)b * (NO * T_) + (size_t)o * T_ + t] = s;
        sum += s;
    }
    out[(size_t)(B_ * NO) * T_ + idx] = sum * (1.0f / T_);
}

extern "C" void kernel_launch(void* const* d_in, const int* in_sizes, int n_in,
                              void* d_out, int out_size, void* d_ws, size_t ws_size,
                              hipStream_t stream) {
    const float* spikes = (const float*)d_in[0];   // [128][784][500]
    const float* w_ih   = (const float*)d_in[1];   // [784][256]
    const float* w_ho   = (const float*)d_in[2];   // [256][10]
    float* out = (float*)d_out;                    // 640000 + 1280 floats

    float* I_h = (float*)d_ws;                     // 64000*256 fp32 = 65.5 MB
    float* I_o = I_h + (size_t)M_ * NH;            // 64000*10  fp32 = 2.56 MB

    dim3 gridA(M_ / 128, NH / 128);                // (500, 2)
    gemm_hidden<<<gridA, 256, 0, stream>>>(spikes, w_ih, I_h);
    lif_hidden<<<256, 128, 0, stream>>>(I_h);      // I_h -> s_h in place
    gemm_out<<<512, 256, 0, stream>>>(I_h, w_ho, I_o);
    lif_out<<<5, 256, 0, stream>>>(I_o, out);
}

// Round 2
// 198.054 us; speedup vs baseline: 2.5116x; 2.5116x over previous
//
#include <hip/hip_runtime.h>

// LIF net: time-hoisted bf16 MFMA GEMM (M=64000,K=784->832,N=256) ->
// chunked LIF scan -> skinny GEMM (K=256,N=10) -> output scan.
// ws: Bt (pre-swizzled bf16 B, 416KB) @0 | I_h bf16 31.25MB @512KB | I_o fp32 2.56MB.

typedef __attribute__((ext_vector_type(4))) float  floatx4;
typedef __attribute__((ext_vector_type(8))) short  shortx8;
typedef unsigned short u16;
typedef unsigned int   u32;

#define B_   128
#define NIN  784
#define NH   256
#define NO   10
#define T_   500
#define M_   (B_ * T_)    // 64000
#define KT   13           // ceil(784/64); k in [784,832) zero-padded

__device__ __forceinline__ u16 f2bf(float f) {
    union { float f; u32 u; } x; x.f = f;
    u32 r = x.u + 0x7FFFu + ((x.u >> 16) & 1u);   // RNE
    return (u16)(r >> 16);
}
__device__ __forceinline__ float bf2f(u16 u) {
    union { u32 u; float f; } x; x.u = ((u32)u) << 16; return x.f;
}
__device__ __forceinline__ float sigmoid5(float v) {
    return 1.0f / (1.0f + __expf(-5.0f * (v - 1.0f)));
}
__device__ __forceinline__ int swz8(int r) { return (r & 7) ^ ((r >> 3) & 7); }

// ---------- Pre-pass: Bt[kt][n][kk] bf16, relu'd, XOR-swizzled, zero-padded ----------
__global__ void convert_B(const float* __restrict__ w, u16* __restrict__ Bt) {
    const int k = blockIdx.x;          // 0..831
    const int n = threadIdx.x;         // 0..255
    float f = (k < NIN) ? fmaxf(0.f, w[k * NH + n]) : 0.f;
    const int kt = k >> 6, kk = k & 63;
    Bt[(size_t)kt * (NH * 64) + n * 64 + (kk ^ (swz8(n) << 3))] = f2bf(f);
}

// ---------- Phase A: hidden GEMM, bf16 MFMA ----------
// Tile 128m x 256n, BK=64, 512 thr (8 waves 2x4), wave tile 64x64 (4x4 frags).
// A reg-staged from spikes[b][k][t] (float4 along t=m, 4-aligned so never
// crosses a b boundary since 500%4==0), transposed+cvt in regs, swizzled
// ds_write_b64.  B = linear copy of pre-swizzled Bt.
__global__ __launch_bounds__(512, 2) void gemm_hidden(
    const float* __restrict__ spikes, const u16* __restrict__ Bt,
    u16* __restrict__ Ih)
{
    __shared__ u16 As[128 * 64];   // [m][k] swizzled, rows 128B
    __shared__ u16 Bs[256 * 64];   // [n][k] swizzled (baked into Bt)

    const int tid  = threadIdx.x;
    const int row0 = blockIdx.x * 128;

    // A-staging assignment: thread covers m4..m4+3 x k-quad 4*kq
    const int m4 = (tid & 31) * 4;
    const int kq = tid >> 5;                       // 0..15
    const int gm = row0 + m4;
    const int bb = gm / 500;
    const int tt = gm - bb * 500;
    const float* abase = spikes + (size_t)bb * (NIN * T_) + tt;

    int wIdx[4];
#pragma unroll
    for (int j = 0; j < 4; ++j) {
        const int m = m4 + j;
        wIdx[j] = m * 64 + ((kq * 4) ^ (swz8(m) << 3));
    }

    // frag addresses (u16 units), iter-invariant; ks toggles bit5 (^32)
    const int lane = tid & 63, wid = tid >> 6;
    const int wm = wid >> 2, wn = wid & 3;
    const int lg = lane >> 4, lr = lane & 15;
    int aIdx[4], bIdx[4];
#pragma unroll
    for (int i = 0; i < 4; ++i) {
        const int m = wm * 64 + i * 16 + lr;
        aIdx[i] = m * 64 + ((lg * 8) ^ (swz8(m) << 3));
        const int n = wn * 64 + i * 16 + lr;
        bIdx[i] = n * 64 + ((lg * 8) ^ (swz8(n) << 3));
    }

    floatx4 acc[4][4];
#pragma unroll
    for (int i = 0; i < 4; ++i)
#pragma unroll
        for (int j = 0; j < 4; ++j) acc[i][j] = (floatx4)0.f;

    for (int it = 0; it < KT; ++it) {
        // ---- stage A (load f32 along m, transpose+cvt to k-contig bf16) ----
        const int kb = it * 64 + kq * 4;
        float va[4][4];
        if (kb < NIN) {
#pragma unroll
            for (int i = 0; i < 4; ++i) {
                const floatx4 v = *(const floatx4*)(abase + (size_t)(kb + i) * T_);
#pragma unroll
                for (int j = 0; j < 4; ++j) va[i][j] = v[j];
            }
        } else {
#pragma unroll
            for (int i = 0; i < 4; ++i)
#pragma unroll
                for (int j = 0; j < 4; ++j) va[i][j] = 0.f;
        }
#pragma unroll
        for (int j = 0; j < 4; ++j) {
            uint2 p;
            p.x = (u32)f2bf(va[0][j]) | ((u32)f2bf(va[1][j]) << 16);
            p.y = (u32)f2bf(va[2][j]) | ((u32)f2bf(va[3][j]) << 16);
            *(uint2*)&As[wIdx[j]] = p;
        }
        // ---- stage B: linear 16B copies (swizzle pre-baked) ----
        {
            const u16* src = Bt + (size_t)it * (NH * 64);
#pragma unroll
            for (int c = 0; c < 4; ++c) {
                const int o = c * 4096 + tid * 8;
                *(uint4*)&Bs[o] = *(const uint4*)(src + o);
            }
        }
        __syncthreads();

        // ---- MFMA: 2 K-steps x 4x4 frags ----
#pragma unroll
        for (int ks = 0; ks < 2; ++ks) {
            shortx8 af[4], bfr[4];
#pragma unroll
            for (int i = 0; i < 4; ++i) {
                af[i]  = *(const shortx8*)&As[aIdx[i] ^ (ks * 32)];
                bfr[i] = *(const shortx8*)&Bs[bIdx[i] ^ (ks * 32)];
            }
#pragma unroll
            for (int mi = 0; mi < 4; ++mi)
#pragma unroll
                for (int ni = 0; ni < 4; ++ni)
                    acc[mi][ni] = __builtin_amdgcn_mfma_f32_16x16x32_bf16(
                        af[mi], bfr[ni], acc[mi][ni], 0, 0, 0);
        }
        __syncthreads();
    }

    // ---- epilogue: bf16 store, D layout col=lane&15, row=(lane>>4)*4+r ----
#pragma unroll
    for (int mi = 0; mi < 4; ++mi) {
#pragma unroll
        for (int r = 0; r < 4; ++r) {
            const int m = row0 + wm * 64 + mi * 16 + lg * 4 + r;
            const size_t base = (size_t)m * NH;
#pragma unroll
            for (int ni = 0; ni < 4; ++ni) {
                const int n = wn * 64 + ni * 16 + lr;
                Ih[base + n] = f2bf(acc[mi][ni][r]);
            }
        }
    }
}

// ---------- Phase B: hidden LIF scan, chunked LDS staging, in place ----------
__global__ __launch_bounds__(128) void lif_hidden(u16* __restrict__ Ih) {
    __shared__ u16 buf[64 * 128];
    const int b  = blockIdx.x >> 1;
    const int h0 = (blockIdx.x & 1) << 7;
    const int tid = threadIdx.x;
    const size_t rowbase = (size_t)b * (T_ * NH) + h0;
    float v = 0.f;
    for (int c = 0; c < 8; ++c) {
        const int t0 = c * 64;
        const int nt = (c == 7) ? 52 : 64;
        for (int i = tid; i < nt * 16; i += 128) {     // burst: 16B loads
            const int tr = i >> 4, seg = i & 15;
            *(uint4*)&buf[tr * 128 + seg * 8] =
                *(const uint4*)(Ih + rowbase + (size_t)(t0 + tr) * NH + seg * 8);
        }
        __syncthreads();
        for (int t2 = 0; t2 < nt; ++t2) {
            const float I = bf2f(buf[t2 * 128 + tid]);
            v += (I - v) * 0.1f;
            Ih[rowbase + (size_t)(t0 + t2) * NH + tid] = f2bf(sigmoid5(v));
        }
        __syncthreads();
    }
}

// ---------- Phase C: output GEMM (K=256 -> N=10), wave per row ----------
__global__ __launch_bounds__(256) void gemm_out(
    const u16* __restrict__ Sh, const float* __restrict__ w_ho,
    float* __restrict__ Io)
{
    const int lane = threadIdx.x & 63;
    const int wave = blockIdx.x * 4 + (threadIdx.x >> 6);
    const int nw   = gridDim.x * 4;

    float w[4][NO];
#pragma unroll
    for (int i = 0; i < 4; ++i)
#pragma unroll
        for (int o = 0; o < NO; ++o)
            w[i][o] = fmaxf(0.f, w_ho[(size_t)(lane * 4 + i) * NO + o]);

    for (int m = wave; m < M_; m += nw) {
        const ushort4 sv = *(const ushort4*)(Sh + (size_t)m * NH + lane * 4);
        const float s0 = bf2f(sv.x), s1 = bf2f(sv.y), s2 = bf2f(sv.z), s3 = bf2f(sv.w);
        float acc[NO];
#pragma unroll
        for (int o = 0; o < NO; ++o)
            acc[o] = s0 * w[0][o] + s1 * w[1][o] + s2 * w[2][o] + s3 * w[3][o];
#pragma unroll
        for (int o = 0; o < NO; ++o) {
            float x = acc[o];
            x += __shfl_xor(x, 1);  x += __shfl_xor(x, 2);  x += __shfl_xor(x, 4);
            x += __shfl_xor(x, 8);  x += __shfl_xor(x, 16); x += __shfl_xor(x, 32);
            acc[o] = x;
        }
        float outv = 0.f;
#pragma unroll
        for (int o = 0; o < NO; ++o) outv = (lane == o) ? acc[o] : outv;
        if (lane < NO) Io[(size_t)m * NO + lane] = outv;
    }
}

// ---------- Phase D: output LIF scan, chunked staging ----------
__global__ __launch_bounds__(64) void lif_out(const float* __restrict__ Io,
                                              float* __restrict__ out) {
    __shared__ float buf[100 * NO];
    const int b = blockIdx.x;
    const int tid = threadIdx.x;
    float v = 0.f, sum = 0.f;
    for (int c = 0; c < 5; ++c) {
        const int t0 = c * 100;
        for (int i = tid; i < 100 * NO; i += 64)
            buf[i] = Io[(size_t)b * (T_ * NO) + (size_t)t0 * NO + i];
        __syncthreads();
        if (tid < NO) {
            for (int t2 = 0; t2 < 100; ++t2) {
                const float I = buf[t2 * NO + tid];
                v += (I - v) * 0.1f;
                const float s = sigmoid5(v);
                out[(size_t)b * (NO * T_) + (size_t)tid * T_ + t0 + t2] = s;
                sum += s;
            }
        }
        __syncthreads();
    }
    if (tid < NO) out[(size_t)(B_ * NO) * T_ + b * NO + tid] = sum * (1.0f / T_);
}

extern "C" void kernel_launch(void* const* d_in, const int* in_sizes, int n_in,
                              void* d_out, int out_size, void* d_ws, size_t ws_size,
                              hipStream_t stream) {
    const float* spikes = (const float*)d_in[0];   // [128][784][500]
    const float* w_ih   = (const float*)d_in[1];   // [784][256]
    const float* w_ho   = (const float*)d_in[2];   // [256][10]
    float* out = (float*)d_out;                    // 640000 spikes + 1280 rates

    u16*   Bt = (u16*)d_ws;                                    // 416 KB
    u16*   Ih = (u16*)((char*)d_ws + (1 << 19));               // 31.25 MB bf16
    float* Io = (float*)((char*)d_ws + (1 << 19) + 33554432);  // 2.56 MB f32

    convert_B  <<<KT * 64, 256, 0, stream>>>(w_ih, Bt);        // 832 k-rows
    gemm_hidden<<<M_ / 128, 512, 0, stream>>>(spikes, Bt, Ih); // 500 blocks
    lif_hidden <<<256, 128, 0, stream>>>(Ih);                  // in place -> s_h
    gemm_out   <<<512, 256, 0, stream>>>(Ih, w_ho, Io);
    lif_out    <<<B_, 64, 0, stream>>>(Io, out);
}

// Round 3
// 127.202 us; speedup vs baseline: 3.9106x; 1.5570x over previous
//
#include <hip/hip_runtime.h>

// LIF net on MI355X: bf16 MFMA GEMM (M=64000,K=784->832,N=256, A read once)
// -> fused [hidden LIF scan + output GEMM] -> segmented output LIF scan.
// ws: Bt 416KB @0 | Ih bf16 31.25MB @512KB | IoA 2.56MB | IoB 2.56MB.

typedef __attribute__((ext_vector_type(4))) float  floatx4;
typedef __attribute__((ext_vector_type(8))) short  shortx8;
typedef unsigned short u16;
typedef unsigned int   u32;

#define B_   128
#define NIN  784
#define NH   256
#define NO   10
#define T_   500
#define M_   (B_ * T_)    // 64000
#define KT   13           // ceil(784/64); k in [784,832) zero-padded

__device__ __forceinline__ u16 f2bf(float f) {
    union { float f; u32 u; } x; x.f = f;
    u32 r = x.u + 0x7FFFu + ((x.u >> 16) & 1u);   // RNE
    return (u16)(r >> 16);
}
__device__ __forceinline__ float bf2f(u16 u) {
    union { u32 u; float f; } x; x.u = ((u32)u) << 16; return x.f;
}
__device__ __forceinline__ float sigmoid5(float v) {
    return 1.0f / (1.0f + __expf(-5.0f * (v - 1.0f)));
}
__device__ __forceinline__ int swz8(int r) { return (r & 7) ^ ((r >> 3) & 7); }

// async global->LDS, 16B per lane (dest = wave-uniform base + lane*16)
__device__ __forceinline__ void gload16(const u16* g, u16* l) {
    __builtin_amdgcn_global_load_lds(
        (const __attribute__((address_space(1))) unsigned int*)(const void*)g,
        (__attribute__((address_space(3))) unsigned int*)(void*)l, 16, 0, 0);
}

// ---------- Pre-pass: Bt[kt][n][kk^swz] bf16, relu'd, zero-padded ----------
__global__ void convert_B(const float* __restrict__ w, u16* __restrict__ Bt) {
    const int k = blockIdx.x;          // 0..831
    const int n = threadIdx.x;         // 0..255
    float f = (k < NIN) ? fmaxf(0.f, w[k * NH + n]) : 0.f;
    const int kt = k >> 6, kk = k & 63;
    Bt[(size_t)kt * (NH * 64) + n * 64 + (kk ^ (swz8(n) << 3))] = f2bf(f);
}

// ---------- Phase A: hidden GEMM ----------
// Tile 64m x 256n (A read once), BK=64, 512 thr (8 waves 2x4), wave tile
// 32x64 (2x4 frags, 32 acc regs -> 2 blocks/CU).  Double-buffered LDS
// (2x8KB As + 2x32KB Bs = 80KB), ONE barrier per K-iter.  B staged via
// global_load_lds (swizzle pre-baked in Bt); A reg-prefetched one iter ahead.
__global__ __launch_bounds__(512, 4) void gemm_hidden(
    const float* __restrict__ spikes,   // [128][784][500] f32
    const u16* __restrict__ Bt,
    u16* __restrict__ Ih)               // [64000][256] bf16
{
    __shared__ u16 As[2][64 * 64];
    __shared__ u16 Bs[2][256 * 64];

    const int tid  = threadIdx.x;
    const int row0 = blockIdx.x * 64;

    // A staging: thread = (m-quad, k-duo)
    const int m4  = (tid & 15) * 4;
    const int duo = tid >> 4;                 // k = 2*duo
    const int gm  = row0 + m4;
    const int bb  = gm / 500;
    const int tt  = gm - bb * 500;
    const float* abase = spikes + (size_t)bb * (NIN * T_) + tt;

    int wOff[4];
#pragma unroll
    for (int j = 0; j < 4; ++j) {
        const int m = m4 + j;
        wOff[j] = m * 64 + ((duo * 2) ^ (swz8(m) << 3));
    }

    const int lane = tid & 63, wid = tid >> 6;
    const int wm = wid >> 2, wn = wid & 3;    // wm 0..1, wn 0..3
    const int lg = lane >> 4, lr = lane & 15;
    int aOff[2], bOff[4];
#pragma unroll
    for (int i = 0; i < 2; ++i) {
        const int m = wm * 32 + i * 16 + lr;
        aOff[i] = m * 64 + ((lg * 8) ^ (swz8(m) << 3));
    }
#pragma unroll
    for (int i = 0; i < 4; ++i) {
        const int n = wn * 64 + i * 16 + lr;
        bOff[i] = n * 64 + ((lg * 8) ^ (swz8(n) << 3));
    }

    floatx4 acc[2][4];
#pragma unroll
    for (int i = 0; i < 2; ++i)
#pragma unroll
        for (int j = 0; j < 4; ++j) acc[i][j] = (floatx4)0.f;

#define LOADA(dst, itv) { const int kb = (itv) * 64 + duo * 2;                 \
        if (kb < NIN) {                                                        \
            dst[0] = *(const floatx4*)(abase + (size_t)kb * T_);               \
            dst[1] = *(const floatx4*)(abase + (size_t)(kb + 1) * T_);         \
        } else { dst[0] = (floatx4)0.f; dst[1] = (floatx4)0.f; } }

#define WRITEA(buf, src) { _Pragma("unroll") for (int j = 0; j < 4; ++j) {     \
        u32 p = (u32)f2bf(src[0][j]) | ((u32)f2bf(src[1][j]) << 16);           \
        *(u32*)&As[buf][wOff[j]] = p; } }

#define STAGEB(buf, itv) { const u16* src = Bt + (size_t)(itv) * (NH * 64);    \
        _Pragma("unroll") for (int c = 0; c < 4; ++c) {                        \
            const int o = c * 4096 + tid * 8;                                  \
            gload16(src + o, &Bs[buf][o]); } }

#define MFMAIT(buf) { _Pragma("unroll") for (int ks = 0; ks < 2; ++ks) {       \
        shortx8 af[2], bfv[4];                                                 \
        _Pragma("unroll") for (int i = 0; i < 2; ++i)                          \
            af[i] = *(const shortx8*)&As[buf][aOff[i] ^ (ks * 32)];            \
        _Pragma("unroll") for (int i = 0; i < 4; ++i)                          \
            bfv[i] = *(const shortx8*)&Bs[buf][bOff[i] ^ (ks * 32)];           \
        _Pragma("unroll") for (int mi = 0; mi < 2; ++mi)                       \
        _Pragma("unroll") for (int ni = 0; ni < 4; ++ni)                       \
            acc[mi][ni] = __builtin_amdgcn_mfma_f32_16x16x32_bf16(             \
                af[mi], bfv[ni], acc[mi][ni], 0, 0, 0); } }

    floatx4 vaP[2], vaQ[2];
    LOADA(vaP, 0);
    WRITEA(0, vaP);
    STAGEB(0, 0);
    LOADA(vaQ, 1);
    __syncthreads();

    for (int it = 0; it < KT; ++it) {
        const int cur = it & 1, nxt = cur ^ 1;
        if (it + 1 < KT) {
            STAGEB(nxt, it + 1);
            if (it & 1) { WRITEA(nxt, vaP); } else { WRITEA(nxt, vaQ); }
        }
        if (it + 2 < KT) {
            if (it & 1) { LOADA(vaQ, it + 2); } else { LOADA(vaP, it + 2); }
        }
        MFMAIT(cur);
        __syncthreads();
    }

#pragma unroll
    for (int mi = 0; mi < 2; ++mi)
#pragma unroll
        for (int r = 0; r < 4; ++r) {
            const int m = row0 + wm * 32 + mi * 16 + lg * 4 + r;
            const size_t base = (size_t)m * NH;
#pragma unroll
            for (int ni = 0; ni < 4; ++ni)
                Ih[base + wn * 64 + ni * 16 + lr] = f2bf(acc[mi][ni][r]);
        }
#undef LOADA
#undef WRITEA
#undef STAGEB
#undef MFMAIT
}

// ---------- Fused: hidden LIF scan + output GEMM ----------
// 256 blocks = (b, h-half), 128 thr (2 waves).  Per 64-t chunk: stage I_h
// (double-buffered, global_load_lds prefetch), per-thread v_h scan -> sbuf
// (XOR-swizzled bf16), then 16x16x32 MFMA vs in-reg w_ho frags -> partial
// I_o (per half) to global.  No s_h round-trip to HBM.
__global__ __launch_bounds__(128) void lif_gemm(
    const u16* __restrict__ Ih, const float* __restrict__ w_ho,
    float* __restrict__ IoA, float* __restrict__ IoB)
{
    __shared__ u16 ibuf[2][64 * 128];   // 16KB x2
    __shared__ u16 sbuf[64 * 128];      // 16KB

    const int b    = blockIdx.x >> 1;
    const int half = blockIdx.x & 1;
    const int h0   = half << 7;
    const int tid  = threadIdx.x;
    float* Iop = half ? IoB : IoA;

    const int lane = tid & 63, w = tid >> 6;
    const int lg = lane >> 4, lr = lane & 15;

    // B-frags: bw[ks][j] = relu(w_ho)[k = h0+ks*32+lg*8+j][o=lr], 0 for o>=10
    shortx8 bw[4];
#pragma unroll
    for (int ks = 0; ks < 4; ++ks) {
#pragma unroll
        for (int j = 0; j < 8; ++j) {
            float f = 0.f;
            if (lr < NO)
                f = fmaxf(0.f, w_ho[(size_t)(h0 + ks * 32 + lg * 8 + j) * NO + lr]);
            bw[ks][j] = (short)f2bf(f);
        }
    }

    const size_t rowbase = (size_t)b * T_ * NH + h0;

#define LOADC(sel, c, nt) { _Pragma("unroll") for (int p = 0; p < 8; ++p) {    \
        const int idx = p * 128 + tid;                                         \
        const int tr = idx >> 4, seg = idx & 15;                               \
        if (tr < (nt))                                                         \
            gload16(Ih + rowbase + (size_t)((c) * 64 + tr) * NH + seg * 8,     \
                    &ibuf[sel][tr * 128 + seg * 8]); } }

    float v = 0.f;
    LOADC(0, 0, 64);
    for (int c = 0; c < 8; ++c) {
        const int sel = c & 1;
        const int nt = (c == 7) ? 52 : 64;
        __syncthreads();                      // chunk c landed; sbuf free
        if (c < 7) { const int nn = (c == 6) ? 52 : 64; LOADC(sel ^ 1, c + 1, nn); }
        for (int t2 = 0; t2 < nt; ++t2) {     // scan (HBM prefetch hides here)
            const float I = bf2f(ibuf[sel][t2 * 128 + tid]);
            v += (I - v) * 0.1f;
            sbuf[t2 * 128 + (tid ^ ((t2 & 7) << 3))] = f2bf(sigmoid5(v));
        }
        __syncthreads();                      // sbuf ready
#pragma unroll
        for (int fi = 0; fi < 2; ++fi) {      // frags f = w, w+2
            const int f = w + fi * 2;
            const int row = f * 16 + lr;
            const int rb = row * 128, sw = (row & 7) << 3;
            floatx4 acc = (floatx4)0.f;
#pragma unroll
            for (int ks = 0; ks < 4; ++ks) {
                const shortx8 a = *(const shortx8*)&sbuf[rb + ((ks * 32 + lg * 8) ^ sw)];
                acc = __builtin_amdgcn_mfma_f32_16x16x32_bf16(a, bw[ks], acc, 0, 0, 0);
            }
#pragma unroll
            for (int r = 0; r < 4; ++r) {
                const int t = c * 64 + f * 16 + lg * 4 + r;
                if (t < T_ && lr < NO)
                    Iop[((size_t)b * T_ + t) * NO + lr] = acc[r];
            }
        }
    }
#undef LOADC
}

// ---------- Output LIF scan: segmented parallel (25 seg x 20 t x 10 o) ----------
__global__ __launch_bounds__(256) void lif_out(
    const float* __restrict__ IoA, const float* __restrict__ IoB,
    float* __restrict__ out)
{
    __shared__ float Isum[T_ * NO];                         // 20KB
    __shared__ float vend[25][NO], vstart[25][NO], psum[25][NO];
    const int b = blockIdx.x, tid = threadIdx.x;
    const size_t base = (size_t)b * T_ * NO;
    for (int i = tid; i < T_ * NO; i += 256)
        Isum[i] = IoA[base + i] + IoB[base + i];
    __syncthreads();
    const int seg = tid / NO, o = tid - seg * NO;
    if (tid < 250) {
        float v = 0.f;
#pragma unroll
        for (int j = 0; j < 20; ++j)
            v += (Isum[(seg * 20 + j) * NO + o] - v) * 0.1f;
        vend[seg][o] = v;
    }
    __syncthreads();
    if (tid < NO) {                          // serial combine, 0.9^20 decay
        float vs = 0.f;
#pragma unroll
        for (int s = 0; s < 25; ++s) {
            vstart[s][tid] = vs;
            vs = vend[s][tid] + 0.12157665459f * vs;
        }
    }
    __syncthreads();
    if (tid < 250) {
        float v = vstart[seg][o], ps = 0.f;
#pragma unroll
        for (int j = 0; j < 20; ++j) {
            const int t = seg * 20 + j;
            v += (Isum[t * NO + o] - v) * 0.1f;
            const float s = sigmoid5(v);
            out[(size_t)b * (NO * T_) + (size_t)o * T_ + t] = s;
            ps += s;
        }
        psum[seg][o] = ps;
    }
    __syncthreads();
    if (tid < NO) {
        float tot = 0.f;
#pragma unroll
        for (int s = 0; s < 25; ++s) tot += psum[s][tid];
        out[(size_t)(B_ * NO) * T_ + b * NO + tid] = tot * (1.0f / T_);
    }
}

extern "C" void kernel_launch(void* const* d_in, const int* in_sizes, int n_in,
                              void* d_out, int out_size, void* d_ws, size_t ws_size,
                              hipStream_t stream) {
    (void)in_sizes; (void)n_in; (void)out_size; (void)ws_size;
    const float* spikes = (const float*)d_in[0];   // [128][784][500]
    const float* w_ih   = (const float*)d_in[1];   // [784][256]
    const float* w_ho   = (const float*)d_in[2];   // [256][10]
    float* out = (float*)d_out;

    u16*   Bt  = (u16*)d_ws;
    u16*   Ih  = (u16*)((char*)d_ws + 524288);
    float* IoA = (float*)((char*)d_ws + 524288 + 32768000);
    float* IoB = (float*)((char*)d_ws + 524288 + 32768000 + 2560000);

    convert_B  <<<KT * 64, 256, 0, stream>>>(w_ih, Bt);
    gemm_hidden<<<M_ / 64, 512, 0, stream>>>(spikes, Bt, Ih);   // 1000 blocks
    lif_gemm   <<<B_ * 2, 128, 0, stream>>>(Ih, w_ho, IoA, IoB);
    lif_out    <<<B_, 256, 0, stream>>>(IoA, IoB, out);
}